// Round 1
// baseline (486.500 us; speedup 1.0000x reference)
//
#include <hip/hip_runtime.h>

#define XSTR 68   // padded LDS row stride (floats); 68*4B rows keep 16B alignment

// ---------------------------------------------------------------------------
// Symmetric-X 64x64 matmul in LDS: D = X^T * Y  (== X*Y when X symmetric).
// Row-major [64][64] buffers, 16x16 thread grid, 4x4 acc per thread.
// Trailing __syncthreads; caller guarantees operands ready and D disjoint.
// ---------------------------------------------------------------------------
__device__ __forceinline__ void mm64(const float* X, const float* Y, float* D,
                                     int tid) {
  const int R = (tid >> 4) << 2;
  const int Cc = (tid & 15) << 2;
  float acc[4][4];
#pragma unroll
  for (int i = 0; i < 4; i++)
#pragma unroll
    for (int j = 0; j < 4; j++) acc[i][j] = 0.f;
#pragma unroll 4
  for (int kk = 0; kk < 64; kk++) {
    float4 a = *(const float4*)&X[(kk << 6) + R];
    float4 bb = *(const float4*)&Y[(kk << 6) + Cc];
    float av[4] = {a.x, a.y, a.z, a.w};
    float bv[4] = {bb.x, bb.y, bb.z, bb.w};
#pragma unroll
    for (int i = 0; i < 4; i++)
#pragma unroll
      for (int j = 0; j < 4; j++) acc[i][j] = fmaf(av[i], bv[j], acc[i][j]);
  }
#pragma unroll
  for (int i = 0; i < 4; i++) {
    *(float4*)&D[((R + i) << 6) + Cc] =
        make_float4(acc[i][0], acc[i][1], acc[i][2], acc[i][3]);
  }
  __syncthreads();
}

// ---------------------------------------------------------------------------
// Stage 1: raw second moments S[b] += Xg*Xh, rowsums[b][g] += sum(Xg).
// grid 512 = B(32) x part(16); part -> k = part>>2, pixel base = (part&3)*1024.
// 128 threads = 2 waves; each wave owns a private transposed 64x64 tile and
// processes 8 disjoint 64-pixel chunks (no barriers in hot loop).
// ---------------------------------------------------------------------------
__global__ __launch_bounds__(128) void k_stats(const float* __restrict__ x,
                                               const int* __restrict__ idx,
                                               float* __restrict__ sumw,
                                               float* __restrict__ sigw) {
  __shared__ __align__(16) float Xt[2][64 * XSTR];  // [c][r] transposed tiles
  __shared__ float Ssh[4096];
  __shared__ int chan[64];
  const int tid = threadIdx.x;
  const int wave = tid >> 6, lane = tid & 63;
  const int blk = blockIdx.x;
  const int b = blk >> 4, part = blk & 15;
  const int k = part >> 2;
  const int pbase = (part & 3) << 10;

  if (tid < 64) chan[tid] = idx[(tid << 2) + k];
#pragma unroll
  for (int i = 0; i < 32; i++) Ssh[(i << 7) + tid] = 0.f;
  __syncthreads();

  const float* xb = x + ((size_t)b << 20);
  float* Xw = Xt[wave];
  const int R = (lane >> 3) << 3;   // acc rows (g)
  const int Cc = (lane & 7) << 3;   // acc cols (g)
  float acc[8][8];
#pragma unroll
  for (int i = 0; i < 8; i++)
#pragma unroll
    for (int j = 0; j < 8; j++) acc[i][j] = 0.f;
  float rs8[8];
#pragma unroll
  for (int i = 0; i < 8; i++) rs8[i] = 0.f;

  for (int ch = 0; ch < 8; ch++) {
    const int p0 = pbase + (((ch << 1) + wave) << 6);
    // load 64x64 tile, transposed into LDS via b128 column stores
#pragma unroll
    for (int j = 0; j < 16; j++) {
      const int h4 = j << 2;
      float v0 = xb[((size_t)chan[h4 + 0] << 12) + p0 + lane];
      float v1 = xb[((size_t)chan[h4 + 1] << 12) + p0 + lane];
      float v2 = xb[((size_t)chan[h4 + 2] << 12) + p0 + lane];
      float v3 = xb[((size_t)chan[h4 + 3] << 12) + p0 + lane];
      *(float4*)&Xw[lane * XSTR + h4] = make_float4(v0, v1, v2, v3);
    }
    // compute: S += outer products over 64 columns
#pragma unroll 2
    for (int kk = 0; kk < 64; kk++) {
      const float* row = &Xw[kk * XSTR];
      float4 a0 = *(const float4*)&row[R];
      float4 a1 = *(const float4*)&row[R + 4];
      float4 b0 = *(const float4*)&row[Cc];
      float4 b1 = *(const float4*)&row[Cc + 4];
      float av[8] = {a0.x, a0.y, a0.z, a0.w, a1.x, a1.y, a1.z, a1.w};
      float bv[8] = {b0.x, b0.y, b0.z, b0.w, b1.x, b1.y, b1.z, b1.w};
#pragma unroll
      for (int i = 0; i < 8; i++) {
        rs8[i] += av[i];
#pragma unroll
        for (int j = 0; j < 8; j++) acc[i][j] = fmaf(av[i], bv[j], acc[i][j]);
      }
    }
  }
  __syncthreads();
  // block reduce into Ssh (shared atomics), then one global atomic pass
#pragma unroll
  for (int i = 0; i < 8; i++)
#pragma unroll
    for (int j = 0; j < 8; j++)
      atomicAdd(&Ssh[((R + i) << 6) + Cc + j], acc[i][j]);
  if ((lane & 7) == 0) {  // rs8 identical across gx lanes; commit once
#pragma unroll
    for (int i = 0; i < 8; i++) atomicAdd(&sumw[(b << 6) + R + i], rs8[i]);
  }
  __syncthreads();
#pragma unroll
  for (int i = 0; i < 32; i++) {
    const int e = (i << 7) + tid;
    atomicAdd(&sigw[(b << 12) + e], Ssh[e]);
  }
}

// ---------------------------------------------------------------------------
// Stage 2: per-batch sigma build + Newton-Schulz (T=5) entirely in LDS.
// One block per batch (32 x 256). Exactly 64 KiB LDS (4 x 64x64 fp32).
// ---------------------------------------------------------------------------
__global__ __launch_bounds__(256) void k_ns(const float* __restrict__ sumw,
                                            const float* __restrict__ sigw,
                                            float* __restrict__ meanw,
                                            float* __restrict__ wmw) {
  __shared__ __align__(16) float buf[4][4096];
  float* SN = buf[0];
  float* Pm = buf[1];
  float* Ta = buf[2];
  float* Tb = buf[3];
  const int tid = threadIdx.x;
  const int b = blockIdx.x;

  if (tid < 64) Ta[tid] = sumw[(b << 6) + tid] * (1.f / 16384.f);  // mean
  __syncthreads();
#pragma unroll
  for (int i = 0; i < 16; i++) {
    const int e = (i << 8) + tid;
    const int g = e >> 6, h = e & 63;
    SN[e] = sigw[(b << 12) + e] * (1.f / 16384.f) - Ta[g] * Ta[h];
  }
  if (tid < 64) meanw[(b << 6) + tid] = Ta[tid];
  __syncthreads();
  if (tid < 64) Tb[tid] = SN[tid * 65];  // diagonal
  __syncthreads();
  if (tid == 0) {
    float t = 0.f;
    for (int g = 0; g < 64; g++) t += Tb[g];
    Tb[64] = 1.0f / t;
  }
  __syncthreads();
  const float trinv = Tb[64];
#pragma unroll
  for (int i = 0; i < 16; i++) {
    const int e = (i << 8) + tid;
    SN[e] *= trinv;
    Pm[e] = ((e >> 6) == (e & 63)) ? 1.f : 0.f;
  }
  __syncthreads();

  for (int it = 0; it < 5; it++) {
    mm64(Pm, Pm, Ta, tid);  // Ta = P^2
    mm64(Ta, Pm, Tb, tid);  // Tb = P^3
    mm64(Tb, SN, Ta, tid);  // Ta = P^3 * sigma_N
#pragma unroll
    for (int i = 0; i < 16; i++) {
      const int e = (i << 8) + tid;
      Pm[e] = 1.5f * Pm[e] - 0.5f * Ta[e];
    }
    __syncthreads();
  }
  const float s = sqrtf(trinv);
#pragma unroll
  for (int i = 0; i < 16; i++) {
    const int e = (i << 8) + tid;
    wmw[(b << 12) + e] = Pm[e] * s;
  }
}

// ---------------------------------------------------------------------------
// Stage 3: batch sqrtvar (ddof=1) of wm (4096 entries) and mean (64 entries).
// ---------------------------------------------------------------------------
__global__ __launch_bounds__(256) void k_var(const float* __restrict__ wmw,
                                             const float* __restrict__ meanw,
                                             float* __restrict__ svw,
                                             float* __restrict__ svm) {
  const int tid = threadIdx.x, blk = blockIdx.x;
  if (blk < 16) {
    const int e = (blk << 8) + tid;
    float v[32];
    float s = 0.f;
#pragma unroll
    for (int b = 0; b < 32; b++) {
      v[b] = wmw[(b << 12) + e];
      s += v[b];
    }
    const float mu = s * (1.f / 32.f);
    float s2 = 0.f;
#pragma unroll
    for (int b = 0; b < 32; b++) {
      const float d = v[b] - mu;
      s2 = fmaf(d, d, s2);
    }
    svw[e] = sqrtf(s2 * (1.f / 31.f) + 1e-5f);
  } else if (tid < 64) {
    float v[32];
    float s = 0.f;
#pragma unroll
    for (int b = 0; b < 32; b++) {
      v[b] = meanw[(b << 6) + tid];
      s += v[b];
    }
    const float mu = s * (1.f / 32.f);
    float s2 = 0.f;
#pragma unroll
    for (int b = 0; b < 32; b++) {
      const float d = v[b] - mu;
      s2 = fmaf(d, d, s2);
    }
    svm[tid] = sqrtf(s2 * (1.f / 31.f) + 1e-5f);
  }
}

// ---------------------------------------------------------------------------
// Stage 4: gamma = triu(wir)+triu(wir,1)^T, A = gamma@wm,
//          ofs = mean + eps2*svm - A@mean. One block per batch.
// ---------------------------------------------------------------------------
__global__ __launch_bounds__(256) void k_gA(
    const float* __restrict__ wmw, const float* __restrict__ meanw,
    const float* __restrict__ eps1, const float* __restrict__ eps2,
    const float* __restrict__ svw, const float* __restrict__ svm,
    float* __restrict__ Am, float* __restrict__ ofsw) {
  __shared__ __align__(16) float Wl[4096];
  __shared__ __align__(16) float Gm[4096];
  __shared__ __align__(16) float Al[4096];
  __shared__ float ml[64];
  const int tid = threadIdx.x;
  const int b = blockIdx.x;
  if (tid < 64) ml[tid] = meanw[(b << 6) + tid];
#pragma unroll
  for (int i = 0; i < 16; i++) {
    const int e = (i << 8) + tid;
    Wl[e] = wmw[(b << 12) + e];
  }
  __syncthreads();
#pragma unroll
  for (int i = 0; i < 16; i++) {
    const int e = (i << 8) + tid;
    const int g = e >> 6, h = e & 63;
    const int eu = (h >= g) ? e : ((h << 6) + g);  // mirror lower from upper
    Gm[e] = Wl[eu] + eps1[(b << 12) + eu] * svw[eu];
  }
  __syncthreads();
  mm64(Gm, Wl, Al, tid);  // Al = gamma @ wm (Gm bitwise symmetric)
#pragma unroll
  for (int i = 0; i < 16; i++) {
    const int e = (i << 8) + tid;
    Am[(b << 12) + e] = Al[e];
  }
  if (tid < 64) {
    float dot = 0.f;
    for (int h = 0; h < 64; h++) dot = fmaf(Al[(tid << 6) + h], ml[h], dot);
    ofsw[(b << 6) + tid] = ml[tid] + eps2[(b << 6) + tid] * svm[tid] - dot;
  }
}

// ---------------------------------------------------------------------------
// Stage 5: out[b, idx[4g+k], p] = sum_h A[g,h]*x[b, idx[4h+k], p] + ofs[g].
// Same wave-private tiling as k_stats, but row-major X tile (no transpose).
// ---------------------------------------------------------------------------
__global__ __launch_bounds__(128) void k_apply(const float* __restrict__ x,
                                               const int* __restrict__ idx,
                                               const float* __restrict__ Am,
                                               const float* __restrict__ ofsw,
                                               float* __restrict__ out) {
  __shared__ __align__(16) float AT[64 * XSTR];  // AT[h][g] = A[g][h]
  __shared__ __align__(16) float Xt[2][64 * XSTR];
  __shared__ float ofsl[64];
  __shared__ int chan[64];
  const int tid = threadIdx.x;
  const int wave = tid >> 6, lane = tid & 63;
  const int blk = blockIdx.x;
  const int b = blk >> 4, part = blk & 15;
  const int k = part >> 2;
  const int pbase = (part & 3) << 10;

  if (tid < 64) {
    chan[tid] = idx[(tid << 2) + k];
    ofsl[tid] = ofsw[(b << 6) + tid];
  }
#pragma unroll
  for (int j = 0; j < 32; j++) {
    const int e = (j << 7) + tid;
    const int g = e >> 6, h = e & 63;
    AT[h * XSTR + g] = Am[(b << 12) + e];
  }
  __syncthreads();

  const float* xb = x + ((size_t)b << 20);
  float* outb = out + ((size_t)b << 20);
  float* Xw = Xt[wave];
  const int R = (lane >> 3) << 3;   // output g rows
  const int Cc = (lane & 7) << 3;   // pixel cols

  for (int ch = 0; ch < 8; ch++) {
    const int p0 = pbase + (((ch << 1) + wave) << 6);
#pragma unroll
    for (int j = 0; j < 16; j++) {
      const int h = (j << 2) + (lane >> 4);
      const int c4 = (lane & 15) << 2;
      *(float4*)&Xw[h * XSTR + c4] =
          *(const float4*)&xb[((size_t)chan[h] << 12) + p0 + c4];
    }
    float acc[8][8];
#pragma unroll
    for (int i = 0; i < 8; i++) {
      const float o = ofsl[R + i];
#pragma unroll
      for (int j = 0; j < 8; j++) acc[i][j] = o;
    }
#pragma unroll 2
    for (int h = 0; h < 64; h++) {
      const float* arow = &AT[h * XSTR];
      const float* xrow = &Xw[h * XSTR];
      float4 a0 = *(const float4*)&arow[R];
      float4 a1 = *(const float4*)&arow[R + 4];
      float4 b0 = *(const float4*)&xrow[Cc];
      float4 b1 = *(const float4*)&xrow[Cc + 4];
      float av[8] = {a0.x, a0.y, a0.z, a0.w, a1.x, a1.y, a1.z, a1.w};
      float bv[8] = {b0.x, b0.y, b0.z, b0.w, b1.x, b1.y, b1.z, b1.w};
#pragma unroll
      for (int i = 0; i < 8; i++)
#pragma unroll
        for (int j = 0; j < 8; j++) acc[i][j] = fmaf(av[i], bv[j], acc[i][j]);
    }
#pragma unroll
    for (int i = 0; i < 8; i++) {
      float* dst = outb + ((size_t)chan[R + i] << 12) + p0 + Cc;
      *(float4*)&dst[0] = make_float4(acc[i][0], acc[i][1], acc[i][2], acc[i][3]);
      *(float4*)&dst[4] = make_float4(acc[i][4], acc[i][5], acc[i][6], acc[i][7]);
    }
  }
}

// ---------------------------------------------------------------------------
// Workspace layout (floats):
//   sumw   @ 0        (2048)   -- zeroed
//   sigw   @ 2048     (131072) -- zeroed
//   meanw  @ 133120   (2048)
//   wmw    @ 135168   (131072)
//   Am     @ 266240   (131072)
//   ofsw   @ 397312   (2048)
//   svw    @ 399360   (4096)
//   svm    @ 403456   (64)
// total 403520 floats = 1,614,080 bytes
// ---------------------------------------------------------------------------
extern "C" void kernel_launch(void* const* d_in, const int* in_sizes, int n_in,
                              void* d_out, int out_size, void* d_ws,
                              size_t ws_size, hipStream_t stream) {
  const float* x = (const float*)d_in[0];
  const int* idx = (const int*)d_in[1];
  const float* eps1 = (const float*)d_in[2];
  const float* eps2 = (const float*)d_in[3];
  float* out = (float*)d_out;
  float* ws = (float*)d_ws;

  float* sumw = ws;
  float* sigw = ws + 2048;
  float* meanw = ws + 133120;
  float* wmw = ws + 135168;
  float* Am = ws + 266240;
  float* ofsw = ws + 397312;
  float* svw = ws + 399360;
  float* svm = ws + 403456;

  hipMemsetAsync(d_ws, 0, (2048 + 131072) * sizeof(float), stream);
  k_stats<<<512, 128, 0, stream>>>(x, idx, sumw, sigw);
  k_ns<<<32, 256, 0, stream>>>(sumw, sigw, meanw, wmw);
  k_var<<<17, 256, 0, stream>>>(wmw, meanw, svw, svm);
  k_gA<<<32, 256, 0, stream>>>(wmw, meanw, eps1, eps2, svw, svm, Am, ofsw);
  k_apply<<<512, 128, 0, stream>>>(x, idx, Am, ofsw, out);
}